// Round 5
// baseline (116.362 us; speedup 1.0000x reference)
//
#include <hip/hip_runtime.h>

typedef unsigned short u16;
typedef unsigned int u32;
typedef __bf16 bf16x8 __attribute__((ext_vector_type(8)));
typedef float f32x4 __attribute__((ext_vector_type(4)));
typedef unsigned short u16x8 __attribute__((ext_vector_type(8)));

#define B_ 2
#define T_ 2048
#define K_ 1024
#define H_ 16
#define S_ 64
#define MKC 4194304   // B_*T_*K_
#define QSCALE 0.04508422f  // log2(e)/32 -> QK logits in log2-domain

__device__ __forceinline__ u16 f2bf(float f) {
  unsigned int u = __builtin_bit_cast(unsigned int, f);
  u += 0x7fffu + ((u >> 16) & 1u);
  return (u16)(u >> 16);
}

__device__ __forceinline__ f32x4 MFMA(bf16x8 a, bf16x8 b, f32x4 c) {
  return __builtin_amdgcn_mfma_f32_16x16x32_bf16(a, b, c, 0, 0, 0);
}

__device__ __forceinline__ void gld16(const void* g, void* l) {
  __builtin_amdgcn_global_load_lds((const __attribute__((address_space(1))) void*)g,
                                   (__attribute__((address_space(3))) void*)l, 16, 0, 0);
}

// ---------------- fp32 -> bf16: x + 4 weight matrices, one launch ----------------
__global__ __launch_bounds__(256) void cvt_all(const float* __restrict__ x,
                                               const float* __restrict__ W0,
                                               const float* __restrict__ W1,
                                               const float* __restrict__ W2,
                                               const float* __restrict__ W3,
                                               u16* __restrict__ xb,
                                               u16* __restrict__ wb) {
  const int i = blockIdx.x * 256 + threadIdx.x;  // 8-elem units
  const float* src;
  u16* dst;
  if (i < 524288) {
    src = x + (size_t)i * 8;
    dst = xb + (size_t)i * 8;
  } else {
    const int j = i - 524288;
    const int sel = j >> 17;  // block-uniform
    const float* W = sel == 0 ? W0 : sel == 1 ? W1 : sel == 2 ? W2 : W3;
    src = W + (size_t)(j & 131071) * 8;
    dst = wb + (size_t)j * 8;
  }
  const float4* s = (const float4*)src;
  float4 f0 = s[0], f1 = s[1];
  u16x8 p;
  p[0] = f2bf(f0.x); p[1] = f2bf(f0.y); p[2] = f2bf(f0.z); p[3] = f2bf(f0.w);
  p[4] = f2bf(f1.x); p[5] = f2bf(f1.y); p[6] = f2bf(f1.z); p[7] = f2bf(f1.w);
  *(u16x8*)dst = p;
}

// ------- GEMM, double-buffered LDS (T3-minimum): C = A[M,K]*B[N,K]^T + bias -------
// OMODE 3 (BN=128): fused QKV epilogue, N=3072. sel=bn>>10: Q (xQSCALE), K natural
//   bf16; V -> Vt[b,h,s,t]. OMODE 2 (BN=64): f32 natural, bias b0.
template <int OMODE, int BN>
__global__ __launch_bounds__(256) void gemm16(const u16* __restrict__ A,
                                              const u16* __restrict__ Bm,
                                              const float* __restrict__ b0,
                                              const float* __restrict__ b1,
                                              const float* __restrict__ b2,
                                              void* __restrict__ C0,
                                              int M, int N, int K) {
  constexpr int NF = BN / 32;
  __shared__ u16 As[2][128 * 32];
  __shared__ u16 Bs[2][BN * 32];
  const int bm = blockIdx.x * 128;
  const int bn = blockIdx.y * BN;
  const int tid = threadIdx.x;
  const int w = tid >> 6, lane = tid & 63;
  const int wr = (w >> 1) * 64, wc = (w & 1) * (BN / 2);
  const int lr = lane & 15, g = lane >> 4;
  const int lk = g * 8;
  const int srow = lane >> 2, scol = (lane & 3) * 8;

  f32x4 acc[4][NF] = {};

  auto stg = [&](int buf, int k0) {
#pragma unroll
    for (int i = 0; i < 2; ++i) {
      const int rbase = (i * 4 + w) * 16;
      gld16(A + (size_t)(bm + rbase + srow) * K + k0 + scol, &As[buf][rbase * 32]);
    }
#pragma unroll
    for (int i = 0; i < BN / 64; ++i) {
      const int rbase = (i * 4 + w) * 16;
      gld16(Bm + (size_t)(bn + rbase + srow) * K + k0 + scol, &Bs[buf][rbase * 32]);
    }
  };

  stg(0, 0);
  asm volatile("s_waitcnt vmcnt(0)" ::: "memory");
  __syncthreads();

  for (int k0 = 0; k0 < K; k0 += 32) {
    const int buf = (k0 >> 5) & 1;
    if (k0 + 32 < K) stg(buf ^ 1, k0 + 32);
    bf16x8 af[4], bfr[NF];
#pragma unroll
    for (int m = 0; m < 4; ++m)
      af[m] = *(const bf16x8*)&As[buf][(wr + m * 16 + lr) * 32 + lk];
#pragma unroll
    for (int n = 0; n < NF; ++n)
      bfr[n] = *(const bf16x8*)&Bs[buf][(wc + n * 16 + lr) * 32 + lk];
#pragma unroll
    for (int m = 0; m < 4; ++m)
#pragma unroll
      for (int n = 0; n < NF; ++n)
        acc[m][n] = MFMA(af[m], bfr[n], acc[m][n]);
    asm volatile("s_waitcnt vmcnt(0)" ::: "memory");
    __syncthreads();
  }

  const int sel = (OMODE == 2) ? 0 : (bn >> 10);
  const float* bp = (OMODE == 2) ? b0 : (sel == 0 ? b0 : sel == 1 ? b1 : b2);
#pragma unroll
  for (int n = 0; n < NF; ++n) {
    const int col = bn + wc + n * 16 + lr;
    const float bv = bp[(OMODE == 2) ? col : (col & 1023)];
#pragma unroll
    for (int m = 0; m < 4; ++m) {
#pragma unroll
      for (int r = 0; r < 4; ++r) {
        const int row = bm + wr + m * 16 + g * 4 + r;
        float v = acc[m][n][r] + bv;
        if (OMODE == 2) {
          ((float*)C0)[(size_t)row * N + col] = v;
        } else {
          u16* dst = (u16*)C0;
          const int cc = col & 1023;
          if (sel == 2) {
            const int bb = row >> 11, t = row & 2047, hh = cc >> 6, ss = cc & 63;
            dst[(size_t)2 * MKC + (((size_t)(bb * H_ + hh) * S_ + ss) << 11) + t] = f2bf(v);
          } else {
            if (sel == 0) v *= QSCALE;
            dst[(size_t)sel * MKC + (size_t)row * 1024 + cc] = f2bf(v);
          }
        }
      }
    }
  }
}

// ------------- Flash attention, swapped-QK^T, KVBLK=128, K+V in LDS -------------
// Q pre-scaled by log2(e)/32. Grid x=bh, y->qtile {t7,31-t7,8+t7,23-t7} so paired
// co-resident blocks run equal iter counts (uniform finish, no tail decay).
__global__ __launch_bounds__(256) void attn_fwd(const u16* __restrict__ Q,
                                                const u16* __restrict__ Kb,
                                                const u16* __restrict__ Vt,
                                                u16* __restrict__ O) {
  __shared__ u16 Ks[2][128 * 64];  // [kv][d], 128B rows (8 slots), XOR-swizzled
  __shared__ u16 Vs[2][64 * 128];  // [s][t], 256B rows (16 slots), XOR-swizzled
  __shared__ u32 Ps[4][16 * 64];   // per-wave P: 16 q x 128 kv bf16
  const int tid = threadIdx.x;
  const int w = tid >> 6, lane = tid & 63;
  const int qh = lane & 15;
  const int g = lane >> 4;
  const int bh = blockIdx.x;
  const int b = bh >> 4, h = bh & 15;
  const int yy = blockIdx.y, t7 = yy & 7, kq = yy >> 3;
  const int qtile = (kq == 0) ? t7 : (kq == 1) ? (31 - t7) : (kq == 2) ? (8 + t7) : (23 - t7);
  const int qb = qtile * 64;
  const int qw = qb + w * 16;
  const int myq = qw + qh;

  const size_t qoff = (size_t)(b * T_ + qw + qh) * K_ + h * S_ + g * 8;
  const bf16x8 bq0 = *(const bf16x8*)(Q + qoff);
  const bf16x8 bq1 = *(const bf16x8*)(Q + qoff + 32);

  // K stage: wave w rows [w*32, w*32+32), 4 x gld16 (8 rows each)
  const int krow = lane >> 3;            // 0..7
  const int kslot = (lane & 7) ^ krow;   // pre-swizzled source slot
  // V stage: wave w s-rows [w*16, w*16+16), 4 x gld16 (4 rows each)
  const int vrow = lane >> 4;            // 0..3
  auto stage = [&](int buf, int k0) {
#pragma unroll
    for (int i = 0; i < 4; ++i) {
      const int rb = w * 32 + i * 8;
      gld16(Kb + (size_t)(b * T_ + k0 + rb + krow) * K_ + h * S_ + kslot * 8,
            &Ks[buf][rb * 64]);
    }
#pragma unroll
    for (int i = 0; i < 4; ++i) {
      const int rb = w * 16 + i * 4;              // multiple of 4
      const int row7 = ((i & 1) << 2) | vrow;     // (rb + vrow) & 7
      const int ss = (lane & 15) ^ row7;
      gld16(Vt + (size_t)(bh * S_ + rb + vrow) * T_ + k0 + ss * 8,
            &Vs[buf][rb * 128]);
    }
  };

  const int nk = (qb + 191) >> 7;  // ceil((qb+64)/128)
  stage(0, 0);
  asm volatile("s_waitcnt vmcnt(0)" ::: "memory");
  __syncthreads();

  float m = -INFINITY, lsum = 0.f;
  f32x4 o[4] = {};
  u32* pr = &Ps[w][qh * 64];
  const int sx = (qh & 7) << 2;
  const int ksw = qh & 7;

  for (int kt = 0; kt < nk; ++kt) {
    const int k0 = kt * 128;
    const int cur = kt & 1;
    if (kt + 1 < nk) stage(cur ^ 1, k0 + 128);

    // QK^T (swapped): S^T[kv][q], logits log2-scaled
    f32x4 s[8];
    __builtin_amdgcn_s_setprio(1);
#pragma unroll
    for (int a = 0; a < 8; ++a) {
      const u16* kr = &Ks[cur][(a * 16 + qh) * 64];
      const bf16x8 kf0 = *(const bf16x8*)(kr + ((g ^ ksw) * 8));
      const bf16x8 kf1 = *(const bf16x8*)(kr + (((4 + g) ^ ksw) * 8));
      f32x4 z = {0.f, 0.f, 0.f, 0.f};
      z = MFMA(kf0, bq0, z);
      s[a] = MFMA(kf1, bq1, z);
    }
    __builtin_amdgcn_s_setprio(0);

    float p[8][4];
    float vmax = -INFINITY;
    if (k0 + 127 > qw) {  // wave-uniform: needs causal masking
#pragma unroll
      for (int a = 0; a < 8; ++a)
#pragma unroll
        for (int r = 0; r < 4; ++r) {
          const int kv = k0 + a * 16 + g * 4 + r;
          p[a][r] = (kv <= myq) ? s[a][r] : -INFINITY;
          vmax = fmaxf(vmax, p[a][r]);
        }
    } else {
#pragma unroll
      for (int a = 0; a < 8; ++a)
#pragma unroll
        for (int r = 0; r < 4; ++r) {
          p[a][r] = s[a][r];
          vmax = fmaxf(vmax, p[a][r]);
        }
    }
    vmax = fmaxf(vmax, __shfl_xor(vmax, 16));
    vmax = fmaxf(vmax, __shfl_xor(vmax, 32));

    // defer-max (T13): threshold 8 nats = 11.5 bits
    if (__any(vmax > m + 11.5f)) {
      const float mnew = fmaxf(m, vmax);
      const float alpha = __builtin_amdgcn_exp2f(m - mnew);
      m = mnew;
      lsum *= alpha;
      float aR[4];
#pragma unroll
      for (int r = 0; r < 4; ++r) aR[r] = __shfl(alpha, 4 * g + r);
#pragma unroll
      for (int n = 0; n < 4; ++n)
#pragma unroll
        for (int r = 0; r < 4; ++r) o[n][r] *= aR[r];
    }

    float ls = 0.f;
#pragma unroll
    for (int a = 0; a < 8; ++a)
#pragma unroll
      for (int r = 0; r < 4; ++r) {
        p[a][r] = __builtin_amdgcn_exp2f(p[a][r] - m);
        ls += p[a][r];
      }
    ls += __shfl_xor(ls, 16);
    ls += __shfl_xor(ls, 32);
    lsum += ls;

    // P -> per-wave LDS (swizzled) via cvt_pk, read back as A-frags
#pragma unroll
    for (int a = 0; a < 8; ++a) {
      u32 u0, u1;
      asm("v_cvt_pk_bf16_f32 %0, %1, %2" : "=v"(u0) : "v"(p[a][0]), "v"(p[a][1]));
      asm("v_cvt_pk_bf16_f32 %0, %1, %2" : "=v"(u1) : "v"(p[a][2]), "v"(p[a][3]));
      uint2 uu; uu.x = u0; uu.y = u1;
      *(uint2*)&pr[(8 * a + 2 * g) ^ sx] = uu;
    }
    __builtin_amdgcn_s_setprio(1);
#pragma unroll
    for (int c = 0; c < 4; ++c) {
      const bf16x8 pa = *(const bf16x8*)&pr[(16 * c + 4 * g) ^ sx];
#pragma unroll
      for (int n = 0; n < 4; ++n) {
        const bf16x8 vf =
            *(const bf16x8*)(&Vs[cur][(16 * n + qh) * 128] + (((c * 4 + g) ^ ksw) * 8));
        o[n] = MFMA(pa, vf, o[n]);
      }
    }
    __builtin_amdgcn_s_setprio(0);

    asm volatile("s_waitcnt vmcnt(0)" ::: "memory");
    __syncthreads();
  }

  const float inv = 1.f / lsum;
  float iR[4];
#pragma unroll
  for (int r = 0; r < 4; ++r) iR[r] = __shfl(inv, 4 * g + r);
#pragma unroll
  for (int r = 0; r < 4; ++r) {
    const size_t row = (size_t)(b * T_ + qw + 4 * g + r);
#pragma unroll
    for (int n = 0; n < 4; ++n)
      O[row * K_ + h * S_ + n * 16 + qh] = f2bf(o[n][r] * iR[r]);
  }
}

extern "C" void kernel_launch(void* const* d_in, const int* in_sizes, int n_in,
                              void* d_out, int out_size, void* d_ws, size_t ws_size,
                              hipStream_t stream) {
  (void)in_sizes; (void)n_in; (void)out_size; (void)ws_size;
  const float* x  = (const float*)d_in[0];
  const float* Wq = (const float*)d_in[1];
  const float* bq = (const float*)d_in[2];
  const float* Wk = (const float*)d_in[3];
  const float* bk = (const float*)d_in[4];
  const float* Wv = (const float*)d_in[5];
  const float* bv = (const float*)d_in[6];
  const float* Wo = (const float*)d_in[7];
  const float* bo = (const float*)d_in[8];
  float* out = (float*)d_out;

  const size_t MK = (size_t)MKC;
  const size_t WK = (size_t)K_ * K_;
  u16* Qb  = (u16*)d_ws;      // Q | K | Vt contiguous (gemm16<3> dst)
  u16* Kbf = Qb + MK;
  u16* Vtb = Kbf + MK;
  u16* AO  = Vtb + MK;
  u16* xb  = AO + MK;
  u16* Wqkv = xb + MK;        // Wq|Wk|Wv|Wo bf16 contiguous
  u16* Wob  = Wqkv + 3 * WK;

  dim3 blk(256);
  cvt_all<<<dim3(4096), blk, 0, stream>>>(x, Wq, Wk, Wv, Wo, xb, Wqkv);
  gemm16<3, 128><<<dim3(32, 24), blk, 0, stream>>>(xb, Wqkv, bq, bk, bv, Qb,
                                                   B_ * T_, 3 * K_, K_);
  attn_fwd<<<dim3(B_ * H_, T_ / 64), blk, 0, stream>>>(Qb, Kbf, Vtb, AO);
  gemm16<2, 64><<<dim3(32, 16), blk, 0, stream>>>(AO, Wob, bo, bo, bo, out,
                                                  B_ * T_, K_, K_);
}

// Round 6
// 110.922 us; speedup vs baseline: 1.0490x; 1.0490x over previous
//
#include <hip/hip_runtime.h>

typedef unsigned short u16;
typedef unsigned int u32;
typedef __bf16 bf16x8 __attribute__((ext_vector_type(8)));
typedef float f32x4 __attribute__((ext_vector_type(4)));
typedef unsigned short u16x8 __attribute__((ext_vector_type(8)));
typedef unsigned int u32x4 __attribute__((ext_vector_type(4)));

#define B_ 2
#define T_ 2048
#define K_ 1024
#define H_ 16
#define S_ 64
#define MKC 4194304   // B_*T_*K_
#define QSCALE 0.04508422f  // log2(e)/32 -> QK logits in log2-domain

__device__ __forceinline__ u16 f2bf(float f) {
  unsigned int u = __builtin_bit_cast(unsigned int, f);
  u += 0x7fffu + ((u >> 16) & 1u);
  return (u16)(u >> 16);
}

__device__ __forceinline__ f32x4 MFMA(bf16x8 a, bf16x8 b, f32x4 c) {
  return __builtin_amdgcn_mfma_f32_16x16x32_bf16(a, b, c, 0, 0, 0);
}

__device__ __forceinline__ void gld16(const void* g, void* l) {
  __builtin_amdgcn_global_load_lds((const __attribute__((address_space(1))) void*)g,
                                   (__attribute__((address_space(3))) void*)l, 16, 0, 0);
}

template <int N>
__device__ __forceinline__ void waitv() {
  asm volatile("s_waitcnt vmcnt(%0)" ::"i"(N) : "memory");
}
__device__ __forceinline__ void memfence_barrier() {
  asm volatile("" ::: "memory");
  __builtin_amdgcn_s_barrier();
}

// ---------------- fp32 -> bf16: x + 4 weight matrices, one launch ----------------
__global__ __launch_bounds__(256) void cvt_all(const float* __restrict__ x,
                                               const float* __restrict__ W0,
                                               const float* __restrict__ W1,
                                               const float* __restrict__ W2,
                                               const float* __restrict__ W3,
                                               u16* __restrict__ xb,
                                               u16* __restrict__ wb) {
  const int i = blockIdx.x * 256 + threadIdx.x;  // 8-elem units
  const float* src;
  u16* dst;
  if (i < 524288) {
    src = x + (size_t)i * 8;
    dst = xb + (size_t)i * 8;
  } else {
    const int j = i - 524288;
    const int sel = j >> 17;  // block-uniform
    const float* W = sel == 0 ? W0 : sel == 1 ? W1 : sel == 2 ? W2 : W3;
    src = W + (size_t)(j & 131071) * 8;
    dst = wb + (size_t)j * 8;
  }
  const float4* s = (const float4*)src;
  float4 f0 = s[0], f1 = s[1];
  u16x8 p;
  p[0] = f2bf(f0.x); p[1] = f2bf(f0.y); p[2] = f2bf(f0.z); p[3] = f2bf(f0.w);
  p[4] = f2bf(f1.x); p[5] = f2bf(f1.y); p[6] = f2bf(f1.z); p[7] = f2bf(f1.w);
  *(u16x8*)dst = p;
}

// ------- GEMM, 2-buf LDS + counted vmcnt + raw barriers: C = A*B^T + bias -------
// OMODE 3 (BN=128): fused QKV epilogue, N=3072. sel=bn>>10: Q (xQSCALE), K natural
//   bf16; V -> Vt[b,h,s,t]. OMODE 2 (BN=64): f32 natural, bias b0.
template <int OMODE, int BN>
__global__ __launch_bounds__(256) void gemm16(const u16* __restrict__ A,
                                              const u16* __restrict__ Bm,
                                              const float* __restrict__ b0,
                                              const float* __restrict__ b1,
                                              const float* __restrict__ b2,
                                              void* __restrict__ C0,
                                              int M, int N, int K) {
  constexpr int NF = BN / 32;
  constexpr int SOPS = 2 + BN / 64;  // gld16 per thread per stage
  __shared__ u16 As[2][128 * 32];
  __shared__ u16 Bs[2][BN * 32];
  const int bm = blockIdx.x * 128;
  const int bn = blockIdx.y * BN;
  const int tid = threadIdx.x;
  const int w = tid >> 6, lane = tid & 63;
  const int wr = (w >> 1) * 64, wc = (w & 1) * (BN / 2);
  const int lr = lane & 15, g = lane >> 4;
  const int lk = g * 8;
  const int srow = lane >> 2, scol = (lane & 3) * 8;

  f32x4 acc[4][NF] = {};

  auto stg = [&](int buf, int k0) {
#pragma unroll
    for (int i = 0; i < 2; ++i) {
      const int rbase = (i * 4 + w) * 16;
      gld16(A + (size_t)(bm + rbase + srow) * K + k0 + scol, &As[buf][rbase * 32]);
    }
#pragma unroll
    for (int i = 0; i < BN / 64; ++i) {
      const int rbase = (i * 4 + w) * 16;
      gld16(Bm + (size_t)(bn + rbase + srow) * K + k0 + scol, &Bs[buf][rbase * 32]);
    }
  };

  stg(0, 0);
  const int NK = K >> 5;
  for (int kk = 0; kk < NK; ++kk) {
    const int buf = kk & 1;
    const bool pf = (kk + 1 < NK);
    if (pf) {
      stg(buf ^ 1, (kk + 1) * 32);
      waitv<SOPS>();  // stage(kk) complete; stage(kk+1) stays in flight
    } else {
      waitv<0>();
    }
    __builtin_amdgcn_s_barrier();
    bf16x8 af[4], bfr[NF];
#pragma unroll
    for (int m = 0; m < 4; ++m)
      af[m] = *(const bf16x8*)&As[buf][(wr + m * 16 + lr) * 32 + lk];
#pragma unroll
    for (int n = 0; n < NF; ++n)
      bfr[n] = *(const bf16x8*)&Bs[buf][(wc + n * 16 + lr) * 32 + lk];
#pragma unroll
    for (int m = 0; m < 4; ++m)
#pragma unroll
      for (int n = 0; n < NF; ++n)
        acc[m][n] = MFMA(af[m], bfr[n], acc[m][n]);
    memfence_barrier();  // reads of buf done before next iter overwrites it
  }

  const int sel = (OMODE == 2) ? 0 : (bn >> 10);
  const float* bp = (OMODE == 2) ? b0 : (sel == 0 ? b0 : sel == 1 ? b1 : b2);
#pragma unroll
  for (int n = 0; n < NF; ++n) {
    const int col = bn + wc + n * 16 + lr;
    const float bv = bp[(OMODE == 2) ? col : (col & 1023)];
#pragma unroll
    for (int m = 0; m < 4; ++m) {
#pragma unroll
      for (int r = 0; r < 4; ++r) {
        const int row = bm + wr + m * 16 + g * 4 + r;
        float v = acc[m][n][r] + bv;
        if (OMODE == 2) {
          ((float*)C0)[(size_t)row * N + col] = v;
        } else {
          u16* dst = (u16*)C0;
          const int cc = col & 1023;
          if (sel == 2) {
            const int bb = row >> 11, t = row & 2047, hh = cc >> 6, ss = cc & 63;
            dst[(size_t)2 * MKC + (((size_t)(bb * H_ + hh) * S_ + ss) << 11) + t] = f2bf(v);
          } else {
            if (sel == 0) v *= QSCALE;
            dst[(size_t)sel * MKC + (size_t)row * 1024 + cc] = f2bf(v);
          }
        }
      }
    }
  }
}

// ---- Flash attention: swapped-QK^T, KVBLK=64, P fully in registers ----
// K's global->LDS row map is permuted so each lane's S^T values are exactly its
// PV A-fragment: LDS row rho = a*16+g*4+r holds global kv = (a>>1)*32+g*8+(a&1)*4+r.
// After softmax, pa[c] is built with 4 cvt_pk (no LDS, no shuffles).
// Q pre-scaled by log2(e)/32. Grid x=bh; y->qtile longest-first, quad-balanced.
__global__ __launch_bounds__(256) void attn_fwd(const u16* __restrict__ Q,
                                                const u16* __restrict__ Kb,
                                                const u16* __restrict__ Vt,
                                                u16* __restrict__ O) {
  __shared__ u16 Ks[2][64 * 64];  // [rho][d], 128B rows (8x16B slots), XOR-swizzled
  __shared__ u16 Vs[2][64 * 64];  // [s][t], same layout
  const int tid = threadIdx.x;
  const int w = tid >> 6, lane = tid & 63;
  const int qh = lane & 15;
  const int g = lane >> 4;
  const int bh = blockIdx.x;
  const int b = bh >> 4, h = bh & 15;
  const int yy = blockIdx.y, t7 = yy & 7, kq = yy >> 3;
  const int qtile = (kq == 0) ? (31 - t7) : (kq == 1) ? (16 + t7)
                   : (kq == 2) ? (15 - t7) : t7;
  const int qb = qtile * 64;
  const int qw = qb + w * 16;
  const int myq = qw + qh;

  const size_t qoff = (size_t)(b * T_ + qw + qh) * K_ + h * S_ + g * 8;
  const bf16x8 bq0 = *(const bf16x8*)(Q + qoff);
  const bf16x8 bq1 = *(const bf16x8*)(Q + qoff + 32);

  const int srow = lane >> 3;                 // 0..7
  const int sl8 = ((lane & 7) ^ srow) * 8;    // pre-swizzled d/t slot
  // permuted K source rows (per lane, per i)
  int kvp[2];
#pragma unroll
  for (int i = 0; i < 2; ++i) {
    const int rho = w * 16 + i * 8 + srow;
    const int a = rho >> 4;
    kvp[i] = ((a >> 1) << 5) | (((rho >> 2) & 3) << 3) | ((a & 1) << 2) | (rho & 3);
  }
  auto stage = [&](int buf, int k0) {
#pragma unroll
    for (int i = 0; i < 2; ++i) {
      const int rb = w * 16 + i * 8;
      gld16(Kb + (size_t)(b * T_ + k0 + kvp[i]) * K_ + h * S_ + sl8,
            &Ks[buf][rb * 64]);
    }
#pragma unroll
    for (int i = 0; i < 2; ++i) {
      const int rb = w * 16 + i * 8;
      gld16(Vt + (size_t)(bh * S_ + rb + srow) * T_ + k0 + sl8,
            &Vs[buf][rb * 64]);
    }
  };

  const int nk = qtile + 1;
  stage(0, 0);

  float m = -INFINITY, lsum = 0.f;
  f32x4 o[4] = {};
  const int ksw = qh & 7;

  for (int kt = 0; kt < nk; ++kt) {
    const int k0 = kt * 64;
    const int cur = kt & 1;
    const bool pf = (kt + 1 < nk);
    if (pf) {
      stage(cur ^ 1, k0 + 64);
      waitv<4>();  // stage(kt) done; stage(kt+1) in flight across barrier
    } else {
      waitv<0>();
    }
    __builtin_amdgcn_s_barrier();

    // QK^T (swapped): s[a][r] = S^T[rho=a*16+g*4+r][q=qh], log2-scaled
    f32x4 s[4];
    __builtin_amdgcn_s_setprio(1);
#pragma unroll
    for (int a = 0; a < 4; ++a) {
      const u16* kr = &Ks[cur][(a * 16 + qh) * 64];
      const bf16x8 kf0 = *(const bf16x8*)(kr + ((g ^ ksw) * 8));
      const bf16x8 kf1 = *(const bf16x8*)(kr + (((4 + g) ^ ksw) * 8));
      f32x4 z = {0.f, 0.f, 0.f, 0.f};
      z = MFMA(kf0, bq0, z);
      s[a] = MFMA(kf1, bq1, z);
    }
    __builtin_amdgcn_s_setprio(0);

    // actual kv of s[a][r] = k0 + (a>>1)*32 + g*8 + (a&1)*4 + r
    float p[4][4];
    float vmax = -INFINITY;
    if (k0 + 63 > qw) {  // wave-uniform: needs causal masking
#pragma unroll
      for (int a = 0; a < 4; ++a)
#pragma unroll
        for (int r = 0; r < 4; ++r) {
          const int kv = k0 + ((a >> 1) << 5) + (g << 3) + ((a & 1) << 2) + r;
          p[a][r] = (kv <= myq) ? s[a][r] : -INFINITY;
          vmax = fmaxf(vmax, p[a][r]);
        }
    } else {
#pragma unroll
      for (int a = 0; a < 4; ++a)
#pragma unroll
        for (int r = 0; r < 4; ++r) {
          p[a][r] = s[a][r];
          vmax = fmaxf(vmax, p[a][r]);
        }
    }
    vmax = fmaxf(vmax, __shfl_xor(vmax, 16));
    vmax = fmaxf(vmax, __shfl_xor(vmax, 32));

    // defer-max (T13): threshold 8 nats = 11.5 bits
    if (__any(vmax > m + 11.5f)) {
      const float mnew = fmaxf(m, vmax);
      const float alpha = __builtin_amdgcn_exp2f(m - mnew);
      m = mnew;
      lsum *= alpha;
      float aR[4];
#pragma unroll
      for (int r = 0; r < 4; ++r) aR[r] = __shfl(alpha, 4 * g + r);
#pragma unroll
      for (int n = 0; n < 4; ++n)
#pragma unroll
        for (int r = 0; r < 4; ++r) o[n][r] *= aR[r];
    }

    float ls = 0.f;
#pragma unroll
    for (int a = 0; a < 4; ++a)
#pragma unroll
      for (int r = 0; r < 4; ++r) {
        p[a][r] = __builtin_amdgcn_exp2f(p[a][r] - m);
        ls += p[a][r];
      }
    ls += __shfl_xor(ls, 16);
    ls += __shfl_xor(ls, 32);
    lsum += ls;

    // PV: P already in A-frag order; pack and multiply (no LDS for P)
    __builtin_amdgcn_s_setprio(1);
#pragma unroll
    for (int c = 0; c < 2; ++c) {
      u32 t0, t1, t2, t3;
      asm("v_cvt_pk_bf16_f32 %0, %1, %2" : "=v"(t0) : "v"(p[2 * c][0]), "v"(p[2 * c][1]));
      asm("v_cvt_pk_bf16_f32 %0, %1, %2" : "=v"(t1) : "v"(p[2 * c][2]), "v"(p[2 * c][3]));
      asm("v_cvt_pk_bf16_f32 %0, %1, %2" : "=v"(t2) : "v"(p[2 * c + 1][0]), "v"(p[2 * c + 1][1]));
      asm("v_cvt_pk_bf16_f32 %0, %1, %2" : "=v"(t3) : "v"(p[2 * c + 1][2]), "v"(p[2 * c + 1][3]));
      u32x4 tv; tv[0] = t0; tv[1] = t1; tv[2] = t2; tv[3] = t3;
      const bf16x8 pa = __builtin_bit_cast(bf16x8, tv);
#pragma unroll
      for (int n = 0; n < 4; ++n) {
        const bf16x8 vf =
            *(const bf16x8*)(&Vs[cur][(16 * n + qh) * 64] + (((c * 4 + g) ^ ksw) * 8));
        o[n] = MFMA(pa, vf, o[n]);
      }
    }
    __builtin_amdgcn_s_setprio(0);

    memfence_barrier();  // buf reads done before next iter's stage overwrites
  }

  const float inv = 1.f / lsum;
  float iR[4];
#pragma unroll
  for (int r = 0; r < 4; ++r) iR[r] = __shfl(inv, 4 * g + r);
#pragma unroll
  for (int r = 0; r < 4; ++r) {
    const size_t row = (size_t)(b * T_ + qw + 4 * g + r);
#pragma unroll
    for (int n = 0; n < 4; ++n)
      O[row * K_ + h * S_ + n * 16 + qh] = f2bf(o[n][r] * iR[r]);
  }
}

extern "C" void kernel_launch(void* const* d_in, const int* in_sizes, int n_in,
                              void* d_out, int out_size, void* d_ws, size_t ws_size,
                              hipStream_t stream) {
  (void)in_sizes; (void)n_in; (void)out_size; (void)ws_size;
  const float* x  = (const float*)d_in[0];
  const float* Wq = (const float*)d_in[1];
  const float* bq = (const float*)d_in[2];
  const float* Wk = (const float*)d_in[3];
  const float* bk = (const float*)d_in[4];
  const float* Wv = (const float*)d_in[5];
  const float* bv = (const float*)d_in[6];
  const float* Wo = (const float*)d_in[7];
  const float* bo = (const float*)d_in[8];
  float* out = (float*)d_out;

  const size_t MK = (size_t)MKC;
  const size_t WK = (size_t)K_ * K_;
  u16* Qb  = (u16*)d_ws;      // Q | K | Vt contiguous (gemm16<3> dst)
  u16* Kbf = Qb + MK;
  u16* Vtb = Kbf + MK;
  u16* AO  = Vtb + MK;
  u16* xb  = AO + MK;
  u16* Wqkv = xb + MK;        // Wq|Wk|Wv|Wo bf16 contiguous
  u16* Wob  = Wqkv + 3 * WK;

  dim3 blk(256);
  cvt_all<<<dim3(4096), blk, 0, stream>>>(x, Wq, Wk, Wv, Wo, xb, Wqkv);
  gemm16<3, 128><<<dim3(32, 24), blk, 0, stream>>>(xb, Wqkv, bq, bk, bv, Qb,
                                                   B_ * T_, 3 * K_, K_);
  attn_fwd<<<dim3(B_ * H_, T_ / 64), blk, 0, stream>>>(Qb, Kbf, Vtb, AO);
  gemm16<2, 64><<<dim3(32, 16), blk, 0, stream>>>(AO, Wob, bo, bo, bo, out,
                                                  B_ * T_, K_, K_);
}